// Round 5
// baseline (25390.771 us; speedup 1.0000x reference)
//
#include <hip/hip_runtime.h>
#include <hip/hip_cooperative_groups.h>

namespace cg = cooperative_groups;

#define B_ 64
#define T_ 1024
#define I_ 512
#define H_ 768
#define O_ 512
#define G4 3072          // 4*H
#define JB 16            // j-columns per workgroup
#define NWG 48           // workgroups per direction (H/JB)
#define NWGS 96          // total workgroups

typedef short short8 __attribute__((ext_vector_type(8)));
typedef float f32x4 __attribute__((ext_vector_type(4)));
typedef unsigned long long u64;

// ws layout (bytes):
//   xb  : [T][64 kb][64 b][8] bf16 (k-blocked)            = 67,108,864 B
//   w2  : [2 dir][160 kb][3072 row][8] bf16 (k-blocked)   = 15,728,640 B
//   h2  : [2 dir][2 ring][96 kb][64 b][8] bf16            =    393,216 B
//   bar : 16 counters, 128-B stride                        =      2,048 B
#define XBF_BYTES  (67108864)
#define WCAT_BYTES (15728640)
#define HBUF_BYTES (393216)

__device__ __forceinline__ unsigned short f32_to_bf16(float f) {
    union { float f; unsigned int u; } v; v.f = f;
    unsigned int r = v.u + 0x7fffu + ((v.u >> 16) & 1u);
    return (unsigned short)(r >> 16);
}
__device__ __forceinline__ float sigmoid_f(float x) { return 1.0f / (1.0f + __expf(-x)); }
__device__ __forceinline__ float tanh_f(float x) {
    float e = __expf(2.0f * x);
    return 1.0f - 2.0f / (e + 1.0f);
}

// ---- prep: x (B,T,I) fp32 -> xb [t][kb][b][8] bf16 ---------------------------
__global__ void prep_x_kernel(const float* __restrict__ x, unsigned short* __restrict__ xb) {
    const size_t n = (size_t)B_ * T_ * 64;   // 4,194,304 chunks of 8
    for (size_t i = (size_t)blockIdx.x * blockDim.x + threadIdx.x; i < n;
         i += (size_t)gridDim.x * blockDim.x) {
        int b  = (int)(i >> 16);
        int t  = (int)((i >> 6) & 1023);
        int kb = (int)(i & 63);
        const float4 v0 = *(const float4*)(x + i * 8);
        const float4 v1 = *(const float4*)(x + i * 8 + 4);
        short8 o;
        o[0] = (short)f32_to_bf16(v0.x); o[1] = (short)f32_to_bf16(v0.y);
        o[2] = (short)f32_to_bf16(v0.z); o[3] = (short)f32_to_bf16(v0.w);
        o[4] = (short)f32_to_bf16(v1.x); o[5] = (short)f32_to_bf16(v1.y);
        o[6] = (short)f32_to_bf16(v1.z); o[7] = (short)f32_to_bf16(v1.w);
        *(short8*)(xb + (((size_t)t * 64 + kb) * 64 + b) * 8) = o;
    }
}

// ---- prep: weights fp32 -> w2 k-blocked bf16; zero h ring + counters ---------
__global__ void prep_w_kernel(const float* __restrict__ Wx_f, const float* __restrict__ Wh_f,
                              const float* __restrict__ Wx_b, const float* __restrict__ Wh_b,
                              unsigned short* __restrict__ w2, unsigned short* __restrict__ h2,
                              unsigned* __restrict__ bar) {
    const size_t n = (size_t)2 * G4 * 160;   // 983,040 chunks of 8 k
    for (size_t i = (size_t)blockIdx.x * blockDim.x + threadIdx.x; i < n;
         i += (size_t)gridDim.x * blockDim.x) {
        int dir = (int)(i / 491520);
        int r2  = (int)(i % 491520);
        int row = r2 / 160;
        int kb  = r2 % 160;
        const float* Wx = dir ? Wx_b : Wx_f;
        const float* Wh = dir ? Wh_b : Wh_f;
        const float* src = (kb < 64) ? (Wx + (size_t)row * I_ + kb * 8)
                                     : (Wh + (size_t)row * H_ + (kb - 64) * 8);
        const float4 v0 = *(const float4*)(src);
        const float4 v1 = *(const float4*)(src + 4);
        short8 o;
        o[0] = (short)f32_to_bf16(v0.x); o[1] = (short)f32_to_bf16(v0.y);
        o[2] = (short)f32_to_bf16(v0.z); o[3] = (short)f32_to_bf16(v0.w);
        o[4] = (short)f32_to_bf16(v1.x); o[5] = (short)f32_to_bf16(v1.y);
        o[6] = (short)f32_to_bf16(v1.z); o[7] = (short)f32_to_bf16(v1.w);
        *(short8*)(w2 + (((size_t)dir * 160 + kb) * G4 + row) * 8) = o;
        if (i < 24576) {   // zero all 4 h ring slots (393,216 B)
            short8 z = {0,0,0,0,0,0,0,0};
            *(short8*)(h2 + i * 8) = z;
        }
        if (i < 512) bar[i] = 0u;   // zero barrier counter region
    }
}

// ---- persistent BiLSTM recurrence, k-split waves (A-fragment dedup) ----------
// 96 wgs (2 dir x 48 j-blocks of 16 cols) x 512 thr.
// Waves = (2 mhalf x 4 kquarter). Each wave loads each A-fragment ONCE and
// multiplies by 4 gate B-fragments (h-weights register-resident). Partial z
// reduced across kquarter waves via LDS atomicAdd into bias-pre-init z tile.
__global__ void __launch_bounds__(512, 2)
bilstm_kernel(const float* __restrict__ bias_f, const float* __restrict__ bias_b,
              const unsigned short* __restrict__ xb, const unsigned short* __restrict__ w2,
              unsigned short* h2, unsigned* bar, float* d_out) {
    __shared__ float z_lds[64][68];      // [b][gate*16+jj], pad 4
    __shared__ float c_tile[64][16];

    const int tid   = threadIdx.x;
    const int wg    = blockIdx.x;
    const int dir   = wg / NWG;
    const int j0    = (wg % NWG) * JB;
    const int wave  = tid >> 6;
    const int lane  = tid & 63;
    const int kq    = wave & 3;      // k-quarter
    const int mhalf = wave >> 2;     // 0..1
    const int quad  = lane >> 4;
    const int lrow  = lane & 15;

    for (int i = tid; i < 1024; i += 512) c_tile[i >> 4][i & 15] = 0.0f;

    const float* bptr = dir ? bias_b : bias_f;
    const int m0 = mhalf * 32 + lrow;    // A-row of mtile 0 (mtile 1 = +16)

    // bias registers for z_lds init: thread covers flat [tid*8, tid*8+8)
    float bias_reg[8];
#pragma unroll
    for (int e = 0; e < 8; ++e) {
        int idx = tid * 8 + e;
        int col = idx & 63;
        bias_reg[e] = bptr[(col >> 4) * H_ + j0 + (col & 15)];
    }

    // h-weights register-resident: [gate][s], kb_h = (kq*6+s)*4+quad
    short8 wh[4][6];
#pragma unroll
    for (int g = 0; g < 4; ++g)
#pragma unroll
        for (int s = 0; s < 6; ++s)
            wh[g][s] = *(const short8*)(w2 +
                (((size_t)dir * 160 + 64 + (kq * 6 + s) * 4 + quad) * G4 +
                 g * H_ + j0 + lrow) * 8);

    // striped barrier: 8 counters per dir, 128-B apart
    unsigned* mybar = bar + (dir * 8 + (wg & 7)) * 32;
    unsigned* barbase = bar + dir * 8 * 32;

    // gate-phase mapping: thread -> (b, pair of jj)
    const int gb = tid >> 3;
    const int gj = (tid & 7) * 2;
    const int gjj = j0 + gj;

    // init z_lds with bias
    {
        float* zf = &z_lds[0][0];
#pragma unroll
        for (int e = 0; e < 8; ++e) {
            int idx = tid * 8 + e;
            zf[(idx >> 6) * 68 + (idx & 63)] = bias_reg[e];
        }
    }
    __syncthreads();

    for (int t = 0; t < T_; ++t) {
        const int pb = (t + 1) & 1;
        const int cb = t & 1;
        const int tx = dir ? (T_ - 1 - t) : t;

        f32x4 acc[4][2];
#pragma unroll
        for (int g = 0; g < 4; ++g) {
            acc[g][0] = (f32x4){0.f, 0.f, 0.f, 0.f};
            acc[g][1] = (f32x4){0.f, 0.f, 0.f, 0.f};
        }

        // ---- x-part: K-quarter of 512, A loaded once, 4 gate B-frags ----
#pragma unroll
        for (int s = 0; s < 4; ++s) {
            const int kb = (kq * 4 + s) * 4 + quad;
            const unsigned short* xa = xb + (((size_t)tx * 64 + kb) * 64 + m0) * 8;
            short8 a0 = *(const short8*)(xa);
            short8 a1 = *(const short8*)(xa + 128);
            const unsigned short* wxp = w2 + (((size_t)dir * 160 + kb) * G4 + j0 + lrow) * 8;
#pragma unroll
            for (int g = 0; g < 4; ++g) {
                short8 bf = *(const short8*)(wxp + (size_t)g * H_ * 8);
                acc[g][0] = __builtin_amdgcn_mfma_f32_16x16x32_bf16(a0, bf, acc[g][0], 0, 0, 0);
                acc[g][1] = __builtin_amdgcn_mfma_f32_16x16x32_bf16(a1, bf, acc[g][1], 0, 0, 0);
            }
        }

        // ---- wait: all wgs of my dir finished step t-1 ----
        if (tid == 0) {
            const unsigned tgt = (unsigned)(NWG * t);
            for (;;) {
                unsigned ssum = 0;
#pragma unroll
                for (int i = 0; i < 8; ++i)
                    ssum += __hip_atomic_load(barbase + i * 32, __ATOMIC_RELAXED,
                                              __HIP_MEMORY_SCOPE_AGENT);
                if (ssum >= tgt) break;
                __builtin_amdgcn_s_sleep(1);
            }
        }
        asm volatile("" ::: "memory");
        __syncthreads();

        // ---- h-part: K-quarter of 768, coherent A loads (once), 4 gates ----
        const unsigned short* hbase = h2 + (size_t)(dir * 2 + pb) * 49152;
#pragma unroll
        for (int s = 0; s < 6; ++s) {
            const int kb = (kq * 6 + s) * 4 + quad;
            const u64* p0 = (const u64*)(hbase + ((size_t)kb * 64 + m0) * 8);
            union { u64 u[2]; short8 v; } a0u, a1u;
            a0u.u[0] = __hip_atomic_load(p0,      __ATOMIC_RELAXED, __HIP_MEMORY_SCOPE_AGENT);
            a0u.u[1] = __hip_atomic_load(p0 + 1,  __ATOMIC_RELAXED, __HIP_MEMORY_SCOPE_AGENT);
            a1u.u[0] = __hip_atomic_load(p0 + 32, __ATOMIC_RELAXED, __HIP_MEMORY_SCOPE_AGENT);
            a1u.u[1] = __hip_atomic_load(p0 + 33, __ATOMIC_RELAXED, __HIP_MEMORY_SCOPE_AGENT);
#pragma unroll
            for (int g = 0; g < 4; ++g) {
                acc[g][0] = __builtin_amdgcn_mfma_f32_16x16x32_bf16(a0u.v, wh[g][s], acc[g][0], 0, 0, 0);
                acc[g][1] = __builtin_amdgcn_mfma_f32_16x16x32_bf16(a1u.v, wh[g][s], acc[g][1], 0, 0, 0);
            }
        }

        // ---- reduce partial z across kquarter waves: LDS float atomic add ----
        // C layout: col = lane&15 (=jj), row = quad*4+r (+16*mtile +32*mhalf)
#pragma unroll
        for (int g = 0; g < 4; ++g)
#pragma unroll
            for (int mt = 0; mt < 2; ++mt)
#pragma unroll
                for (int r = 0; r < 4; ++r) {
                    int b = mhalf * 32 + mt * 16 + quad * 4 + r;
                    atomicAdd(&z_lds[b][g * 16 + lrow], acc[g][mt][r]);
                }
        __syncthreads();

        // ---- gates: thread handles (b, jj..jj+1) ----
        {
            unsigned short* hw = h2 + (size_t)(dir * 2 + cb) * 49152;
            float f0 = sigmoid_f(z_lds[gb][gj]);
            float f1 = sigmoid_f(z_lds[gb][gj + 1]);
            float i0 = sigmoid_f(z_lds[gb][16 + gj]);
            float i1 = sigmoid_f(z_lds[gb][16 + gj + 1]);
            float g0 = tanh_f(z_lds[gb][32 + gj]);
            float g1 = tanh_f(z_lds[gb][32 + gj + 1]);
            float o0 = sigmoid_f(z_lds[gb][48 + gj]);
            float o1 = sigmoid_f(z_lds[gb][48 + gj + 1]);
            float c0 = f0 * c_tile[gb][gj]     + i0 * g0;
            float c1 = f1 * c_tile[gb][gj + 1] + i1 * g1;
            c_tile[gb][gj]     = c0;
            c_tile[gb][gj + 1] = c1;
            float h0 = o0 * tanh_f(c0);
            float h1 = o1 * tanh_f(c1);
            unsigned pack = (unsigned)f32_to_bf16(h0) | ((unsigned)f32_to_bf16(h1) << 16);
            unsigned* dst = (unsigned*)(hw + ((gjj >> 3) * 64 + gb) * 8 + (gjj & 7));
            __hip_atomic_store(dst, pack, __ATOMIC_RELAXED, __HIP_MEMORY_SCOPE_AGENT);
            if (t == T_ - 1) {
                int hoff = 32768 + dir * 98304;
                d_out[hoff + gb * H_ + gjj]             = h0;
                d_out[hoff + gb * H_ + gjj + 1]         = h1;
                d_out[hoff + 49152 + gb * H_ + gjj]     = c0;
                d_out[hoff + 49152 + gb * H_ + gjj + 1] = c1;
            }
        }
        __syncthreads();   // z reads done; waves drained vmcnt -> h visible

        // ---- re-init z_lds with bias for next step ----
        {
            float* zf = &z_lds[0][0];
#pragma unroll
            for (int e = 0; e < 8; ++e) {
                int idx = tid * 8 + e;
                zf[(idx >> 6) * 68 + (idx & 63)] = bias_reg[e];
            }
        }

        // ---- arrive ----
        if (tid == 0)
            __hip_atomic_fetch_add(mybar, 1u, __ATOMIC_RELAXED, __HIP_MEMORY_SCOPE_AGENT);
    }
}

// ---- epilogue: out = [h_fwd|h_bwd] @ Why^T + by ------------------------------
__global__ void proj_kernel(float* __restrict__ out, const float* __restrict__ Why,
                            const float* __restrict__ by) {
    __shared__ float hc[2 * H_];
    int b = blockIdx.x;
    const float* hf = out + 32768 + b * H_;
    const float* hb = out + 32768 + 98304 + b * H_;
    for (int i = threadIdx.x; i < H_; i += 256) { hc[i] = hf[i]; hc[H_ + i] = hb[i]; }
    __syncthreads();
    for (int o = threadIdx.x; o < O_; o += 256) {
        const float* wr = Why + (size_t)o * (2 * H_);
        float s = by[o];
        for (int k = 0; k < 2 * H_; k += 4) {
            float4 w = *(const float4*)(wr + k);
            s += w.x * hc[k] + w.y * hc[k + 1] + w.z * hc[k + 2] + w.w * hc[k + 3];
        }
        out[b * O_ + o] = s;
    }
}

extern "C" void kernel_launch(void* const* d_in, const int* in_sizes, int n_in,
                              void* d_out, int out_size, void* d_ws, size_t ws_size,
                              hipStream_t stream) {
    const float* x    = (const float*)d_in[0];
    const float* Wx_f = (const float*)d_in[1];
    const float* Wh_f = (const float*)d_in[2];
    const float* b_f  = (const float*)d_in[3];
    const float* Wx_b = (const float*)d_in[4];
    const float* Wh_b = (const float*)d_in[5];
    const float* b_b  = (const float*)d_in[6];
    const float* Why  = (const float*)d_in[7];
    const float* by   = (const float*)d_in[8];
    float* out = (float*)d_out;

    char* ws = (char*)d_ws;
    unsigned short* xbp = (unsigned short*)(ws);
    unsigned short* w2  = (unsigned short*)(ws + XBF_BYTES);
    unsigned short* h2  = (unsigned short*)(ws + XBF_BYTES + WCAT_BYTES);
    unsigned*       bar = (unsigned*)(ws + XBF_BYTES + WCAT_BYTES + HBUF_BYTES);

    prep_x_kernel<<<8192, 256, 0, stream>>>(x, xbp);
    prep_w_kernel<<<4096, 256, 0, stream>>>(Wx_f, Wh_f, Wx_b, Wh_b, w2, h2, bar);

    void* args[] = {(void*)&b_f, (void*)&b_b, (void*)&xbp, (void*)&w2,
                    (void*)&h2, (void*)&bar, (void*)&out};
    hipLaunchCooperativeKernel((void*)bilstm_kernel, dim3(NWGS), dim3(512), args, 0, stream);

    proj_kernel<<<B_, 256, 0, stream>>>(out, Why, by);
}

// Round 6
// 10308.855 us; speedup vs baseline: 2.4630x; 2.4630x over previous
//
#include <hip/hip_runtime.h>
#include <hip/hip_cooperative_groups.h>

namespace cg = cooperative_groups;

#define B_ 64
#define T_ 1024
#define I_ 512
#define H_ 768
#define O_ 512
#define G4 3072          // 4*H
#define JB 16            // j-columns per workgroup
#define NWG 48           // workgroups per direction (H/JB)
#define NWGS 96          // total workgroups

typedef short short8 __attribute__((ext_vector_type(8)));
typedef float f32x4 __attribute__((ext_vector_type(4)));
typedef unsigned long long u64;

// ws layout (bytes):
//   xb  : [T][64 kb][64 b][8] bf16 (k-blocked)            = 67,108,864 B
//   w2  : [2 dir][160 kb][3072 row][8] bf16 (k-blocked)   = 15,728,640 B
//   h2  : [2 dir][2 ring][96 kb][64 b][8] bf16            =    393,216 B
//   bar : 16 counters, 128-B stride                        =      2,048 B
#define XBF_BYTES  (67108864)
#define WCAT_BYTES (15728640)
#define HBUF_BYTES (393216)

__device__ __forceinline__ unsigned short f32_to_bf16(float f) {
    union { float f; unsigned int u; } v; v.f = f;
    unsigned int r = v.u + 0x7fffu + ((v.u >> 16) & 1u);
    return (unsigned short)(r >> 16);
}
__device__ __forceinline__ float sigmoid_f(float x) { return 1.0f / (1.0f + __expf(-x)); }
__device__ __forceinline__ float tanh_f(float x) {
    float e = __expf(2.0f * x);
    return 1.0f - 2.0f / (e + 1.0f);
}

// ---- prep: x (B,T,I) fp32 -> xb [t][kb][b][8] bf16 ---------------------------
__global__ void prep_x_kernel(const float* __restrict__ x, unsigned short* __restrict__ xb) {
    const size_t n = (size_t)B_ * T_ * 64;   // 4,194,304 chunks of 8
    for (size_t i = (size_t)blockIdx.x * blockDim.x + threadIdx.x; i < n;
         i += (size_t)gridDim.x * blockDim.x) {
        int b  = (int)(i >> 16);
        int t  = (int)((i >> 6) & 1023);
        int kb = (int)(i & 63);
        const float4 v0 = *(const float4*)(x + i * 8);
        const float4 v1 = *(const float4*)(x + i * 8 + 4);
        short8 o;
        o[0] = (short)f32_to_bf16(v0.x); o[1] = (short)f32_to_bf16(v0.y);
        o[2] = (short)f32_to_bf16(v0.z); o[3] = (short)f32_to_bf16(v0.w);
        o[4] = (short)f32_to_bf16(v1.x); o[5] = (short)f32_to_bf16(v1.y);
        o[6] = (short)f32_to_bf16(v1.z); o[7] = (short)f32_to_bf16(v1.w);
        *(short8*)(xb + (((size_t)t * 64 + kb) * 64 + b) * 8) = o;
    }
}

// ---- prep: weights fp32 -> w2 k-blocked bf16; zero h ring + counters ---------
__global__ void prep_w_kernel(const float* __restrict__ Wx_f, const float* __restrict__ Wh_f,
                              const float* __restrict__ Wx_b, const float* __restrict__ Wh_b,
                              unsigned short* __restrict__ w2, unsigned short* __restrict__ h2,
                              unsigned* __restrict__ bar) {
    const size_t n = (size_t)2 * G4 * 160;   // 983,040 chunks of 8 k
    for (size_t i = (size_t)blockIdx.x * blockDim.x + threadIdx.x; i < n;
         i += (size_t)gridDim.x * blockDim.x) {
        int dir = (int)(i / 491520);
        int r2  = (int)(i % 491520);
        int row = r2 / 160;
        int kb  = r2 % 160;
        const float* Wx = dir ? Wx_b : Wx_f;
        const float* Wh = dir ? Wh_b : Wh_f;
        const float* src = (kb < 64) ? (Wx + (size_t)row * I_ + kb * 8)
                                     : (Wh + (size_t)row * H_ + (kb - 64) * 8);
        const float4 v0 = *(const float4*)(src);
        const float4 v1 = *(const float4*)(src + 4);
        short8 o;
        o[0] = (short)f32_to_bf16(v0.x); o[1] = (short)f32_to_bf16(v0.y);
        o[2] = (short)f32_to_bf16(v0.z); o[3] = (short)f32_to_bf16(v0.w);
        o[4] = (short)f32_to_bf16(v1.x); o[5] = (short)f32_to_bf16(v1.y);
        o[6] = (short)f32_to_bf16(v1.z); o[7] = (short)f32_to_bf16(v1.w);
        *(short8*)(w2 + (((size_t)dir * 160 + kb) * G4 + row) * 8) = o;
        if (i < 24576) {   // zero all 4 h ring slots (393,216 B)
            short8 z = {0,0,0,0,0,0,0,0};
            *(short8*)(h2 + i * 8) = z;
        }
        if (i < 512) bar[i] = 0u;   // zero barrier counter region
    }
}

// ---- persistent BiLSTM recurrence: R4 skeleton + LDS h-stage dedup -----------
// 96 wgs (2 dir x 48 j-blocks) x 512 thr (8 waves: gate x mhalf).
// Per step: x-part overlaps barrier arrival; after barrier the wg stages the
// full h_{t-1} (96 KB) into LDS ONCE (coherent 8-B loads, 24/thread), then all
// waves read A-fragments via ds_read_b128 -> 4x less global h traffic than R4.
__global__ void __launch_bounds__(512, 2)
bilstm_kernel(const float* __restrict__ bias_f, const float* __restrict__ bias_b,
              const unsigned short* __restrict__ xb, const unsigned short* __restrict__ w2,
              unsigned short* h2, unsigned* bar, float* d_out) {
    __shared__ unsigned short h_stage[96 * 64 * 8];   // 98,304 B, mirrors h2 slot layout
    __shared__ float z_lds[4][64][17];                // 17,408 B
    __shared__ float c_tile[64][16];                  //  4,096 B

    const int tid   = threadIdx.x;
    const int wg    = blockIdx.x;
    const int dir   = wg / NWG;
    const int j0    = (wg % NWG) * JB;
    const int wave  = tid >> 6;
    const int lane  = tid & 63;
    const int gate  = wave & 3;      // f,i,g,o
    const int mhalf = wave >> 2;
    const int quad  = lane >> 4;
    const int lrow  = lane & 15;

    for (int i = tid; i < 1024; i += 512) c_tile[i >> 4][i & 15] = 0.0f;

    const float bias_r = (dir ? bias_b : bias_f)[gate * H_ + j0 + lrow];
    const int m0 = mhalf * 32 + lrow;
    const int wrow = gate * H_ + j0 + lrow;

    // x-weight base (kb = quad + 4*ks) — stays in L2 (no fences evict it)
    const unsigned short* wx = w2 + (((size_t)dir * 160 + quad) * G4 + wrow) * 8;
    // h-weights: register-resident, constant over all steps (96 VGPR)
    short8 wh[24];
#pragma unroll
    for (int ks = 0; ks < 24; ++ks)
        wh[ks] = *(const short8*)(w2 + (((size_t)dir * 160 + 64 + ks * 4 + quad) * G4 + wrow) * 8);

    // striped barrier: 8 counters per dir, 128-B apart
    unsigned* mybar = bar + (dir * 8 + (wg & 7)) * 32;
    unsigned* barbase = bar + dir * 8 * 32;

    // gate-phase mapping: thread -> (b, pair of j)
    const int gb = tid >> 3;
    const int gj = (tid & 7) * 2;
    const int gjj = j0 + gj;

    __syncthreads();

    for (int t = 0; t < T_; ++t) {
        const int pb = (t + 1) & 1;
        const int cb = t & 1;
        const int tx = dir ? (T_ - 1 - t) : t;

        f32x4 acc0; acc0[0] = bias_r; acc0[1] = bias_r; acc0[2] = bias_r; acc0[3] = bias_r;
        f32x4 acc1 = acc0;

        // ---- x-part (independent of h_{t-1}; overlaps other wgs' arrival) ----
        const unsigned short* xa = xb + (((size_t)tx * 64 + quad) * 64 + m0) * 8;
#pragma unroll
        for (int ks = 0; ks < 16; ++ks) {
            short8 a0 = *(const short8*)(xa + ks * 2048);
            short8 a1 = *(const short8*)(xa + ks * 2048 + 128);
            short8 bf = *(const short8*)(wx + (size_t)ks * 4 * G4 * 8);
            acc0 = __builtin_amdgcn_mfma_f32_16x16x32_bf16(a0, bf, acc0, 0, 0, 0);
            acc1 = __builtin_amdgcn_mfma_f32_16x16x32_bf16(a1, bf, acc1, 0, 0, 0);
        }

        // ---- wait: all wgs of my dir finished step t-1 (relaxed, no fence) ----
        if (tid == 0) {
            const unsigned tgt = (unsigned)(NWG * t);
            for (;;) {
                unsigned ssum = 0;
#pragma unroll
                for (int i = 0; i < 8; ++i)
                    ssum += __hip_atomic_load(barbase + i * 32, __ATOMIC_RELAXED,
                                              __HIP_MEMORY_SCOPE_AGENT);
                if (ssum >= tgt) break;
                __builtin_amdgcn_s_sleep(1);
            }
        }
        asm volatile("" ::: "memory");
        __syncthreads();

        // ---- stage h_{t-1} (96 KB) into LDS once: 24 coherent 8-B loads/thr ----
        {
            const u64* hsrc = (const u64*)(h2 + (size_t)(dir * 2 + pb) * 49152);
            u64* hdst = (u64*)h_stage;
#pragma unroll
            for (int k = 0; k < 24; ++k) {
                u64 v = __hip_atomic_load(hsrc + (size_t)k * 512 + tid,
                                          __ATOMIC_RELAXED, __HIP_MEMORY_SCOPE_AGENT);
                hdst[k * 512 + tid] = v;
            }
        }
        __syncthreads();

        // ---- h-part: K = 768 recurrent, A-fragments from LDS (ds_read_b128) ----
        const unsigned short* ha = h_stage + quad * 512 + m0 * 8;
#pragma unroll
        for (int ks = 0; ks < 24; ++ks) {
            short8 a0 = *(const short8*)(ha + ks * 2048);
            short8 a1 = *(const short8*)(ha + ks * 2048 + 128);
            acc0 = __builtin_amdgcn_mfma_f32_16x16x32_bf16(a0, wh[ks], acc0, 0, 0, 0);
            acc1 = __builtin_amdgcn_mfma_f32_16x16x32_bf16(a1, wh[ks], acc1, 0, 0, 0);
        }

        // z -> LDS (C layout: col=lane&15, row=quad*4+reg)
#pragma unroll
        for (int r = 0; r < 4; ++r) {
            z_lds[gate][mhalf * 32 + quad * 4 + r][lrow]      = acc0[r];
            z_lds[gate][mhalf * 32 + 16 + quad * 4 + r][lrow] = acc1[r];
        }
        __syncthreads();

        // ---- gates: thread handles (b, j..j+1), packed coherent 4-B store ----
        {
            unsigned short* hw = h2 + (size_t)(dir * 2 + cb) * 49152;
            float f0 = sigmoid_f(z_lds[0][gb][gj]);
            float f1 = sigmoid_f(z_lds[0][gb][gj + 1]);
            float i0 = sigmoid_f(z_lds[1][gb][gj]);
            float i1 = sigmoid_f(z_lds[1][gb][gj + 1]);
            float g0 = tanh_f(z_lds[2][gb][gj]);
            float g1 = tanh_f(z_lds[2][gb][gj + 1]);
            float o0 = sigmoid_f(z_lds[3][gb][gj]);
            float o1 = sigmoid_f(z_lds[3][gb][gj + 1]);
            float c0 = f0 * c_tile[gb][gj]     + i0 * g0;
            float c1 = f1 * c_tile[gb][gj + 1] + i1 * g1;
            c_tile[gb][gj]     = c0;
            c_tile[gb][gj + 1] = c1;
            float h0 = o0 * tanh_f(c0);
            float h1 = o1 * tanh_f(c1);
            unsigned pack = (unsigned)f32_to_bf16(h0) | ((unsigned)f32_to_bf16(h1) << 16);
            unsigned* dst = (unsigned*)(hw + ((gjj >> 3) * 64 + gb) * 8 + (gjj & 7));
            __hip_atomic_store(dst, pack, __ATOMIC_RELAXED, __HIP_MEMORY_SCOPE_AGENT);
            if (t == T_ - 1) {
                int hoff = 32768 + dir * 98304;
                d_out[hoff + gb * H_ + gjj]             = h0;
                d_out[hoff + gb * H_ + gjj + 1]         = h1;
                d_out[hoff + 49152 + gb * H_ + gjj]     = c0;
                d_out[hoff + 49152 + gb * H_ + gjj + 1] = c1;
            }
        }
        __syncthreads();   // waves drain vmcnt -> h stores at coherence point

        // ---- arrive (relaxed add to this wg's stripe) ----
        if (tid == 0)
            __hip_atomic_fetch_add(mybar, 1u, __ATOMIC_RELAXED, __HIP_MEMORY_SCOPE_AGENT);
    }
}

// ---- epilogue: out = [h_fwd|h_bwd] @ Why^T + by ------------------------------
__global__ void proj_kernel(float* __restrict__ out, const float* __restrict__ Why,
                            const float* __restrict__ by) {
    __shared__ float hc[2 * H_];
    int b = blockIdx.x;
    const float* hf = out + 32768 + b * H_;
    const float* hb = out + 32768 + 98304 + b * H_;
    for (int i = threadIdx.x; i < H_; i += 256) { hc[i] = hf[i]; hc[H_ + i] = hb[i]; }
    __syncthreads();
    for (int o = threadIdx.x; o < O_; o += 256) {
        const float* wr = Why + (size_t)o * (2 * H_);
        float s = by[o];
        for (int k = 0; k < 2 * H_; k += 4) {
            float4 w = *(const float4*)(wr + k);
            s += w.x * hc[k] + w.y * hc[k + 1] + w.z * hc[k + 2] + w.w * hc[k + 3];
        }
        out[b * O_ + o] = s;
    }
}

extern "C" void kernel_launch(void* const* d_in, const int* in_sizes, int n_in,
                              void* d_out, int out_size, void* d_ws, size_t ws_size,
                              hipStream_t stream) {
    const float* x    = (const float*)d_in[0];
    const float* Wx_f = (const float*)d_in[1];
    const float* Wh_f = (const float*)d_in[2];
    const float* b_f  = (const float*)d_in[3];
    const float* Wx_b = (const float*)d_in[4];
    const float* Wh_b = (const float*)d_in[5];
    const float* b_b  = (const float*)d_in[6];
    const float* Why  = (const float*)d_in[7];
    const float* by   = (const float*)d_in[8];
    float* out = (float*)d_out;

    char* ws = (char*)d_ws;
    unsigned short* xbp = (unsigned short*)(ws);
    unsigned short* w2  = (unsigned short*)(ws + XBF_BYTES);
    unsigned short* h2  = (unsigned short*)(ws + XBF_BYTES + WCAT_BYTES);
    unsigned*       bar = (unsigned*)(ws + XBF_BYTES + WCAT_BYTES + HBUF_BYTES);

    prep_x_kernel<<<8192, 256, 0, stream>>>(x, xbp);
    prep_w_kernel<<<4096, 256, 0, stream>>>(Wx_f, Wh_f, Wx_b, Wh_b, w2, h2, bar);

    void* args[] = {(void*)&b_f, (void*)&b_b, (void*)&xbp, (void*)&w2,
                    (void*)&h2, (void*)&bar, (void*)&out};
    hipLaunchCooperativeKernel((void*)bilstm_kernel, dim3(NWGS), dim3(512), args, 0, stream);

    proj_kernel<<<B_, 256, 0, stream>>>(out, Why, by);
}